// Round 5
// baseline (537.809 us; speedup 1.0000x reference)
//
#include <hip/hip_runtime.h>
#include <math.h>

#define BATCH 8
#define NATOMS 192
#define HF 32

__device__ __forceinline__ float fast_rcp(float x){ return __builtin_amdgcn_rcpf(x); }
__device__ __forceinline__ float sigmoid_f(float x){ return fast_rcp(1.0f+__expf(-x)); }
__device__ __forceinline__ float silu_f(float x){ return x*fast_rcp(1.0f+__expf(-x)); }
__device__ __forceinline__ float softplus_f(float x){ return fmaxf(x,0.0f)+log1pf(expf(-fabsf(x))); }

__device__ __forceinline__ float wave_sum(float v){
  v += __shfl_xor(v, 1);
  v += __shfl_xor(v, 2);
  v += __shfl_xor(v, 4);
  v += __shfl_xor(v, 8);
  v += __shfl_xor(v, 16);
  v += __shfl_xor(v, 32);
  return v;
}

// ---------------- prelude: blocks 0..79 = pdf dot (b,o); 80..87 = gamma(b) --
__global__ __launch_bounds__(256) void k_prelude(
    const float* __restrict__ pdf, const float* __restrict__ t,
    const float* __restrict__ pdf_w, const float* __restrict__ pdf_b,
    const float* __restrict__ g1w, const float* __restrict__ g1b,
    const float* __restrict__ g2w, const float* __restrict__ g2b,
    const float* __restrict__ g3w, const float* __restrict__ g3b,
    const float* __restrict__ gamma0, const float* __restrict__ gamma1,
    float* __restrict__ temb, float* __restrict__ pdfe)
{
  __shared__ float lds[4];
  const int bx = blockIdx.x, tid = threadIdx.x;
  const int wv = tid >> 6, ln = tid & 63;

  if (bx < 80){
    const int b = bx / 10, o = bx % 10;
    const float* pb = pdf + b*3000;
    const float* wb = pdf_w + o*3000;
    float p = 0.f;
    for (int k = tid; k < 3000; k += 256) p = fmaf(pb[k], wb[k], p);
    p = wave_sum(p);
    if (ln == 0) lds[wv] = p;
    __syncthreads();
    if (tid == 0) pdfe[b*10 + o] = lds[0] + lds[1] + lds[2] + lds[3] + pdf_b[o];
    return;
  }
  const int b = bx - 80;
  const float w1 = softplus_f(g1w[0]);
  const float b1 = g1b[0];
  const float tn = t[b] * (1.0f/1000.0f);
  const float l1_0 = b1;
  const float l1_1 = w1 + b1;
  const float l1_t = fmaf(w1, tn, b1);
  float a0 = 0.f, a1 = 0.f, at = 0.f;
  for (int k = tid; k < 1024; k += 256){
    float w2 = softplus_f(g2w[k]);
    float bb = g2b[k];
    float w3 = softplus_f(g3w[k]);
    a0 += sigmoid_f(fmaf(w2, l1_0, bb)) * w3;
    a1 += sigmoid_f(fmaf(w2, l1_1, bb)) * w3;
    at += sigmoid_f(fmaf(w2, l1_t, bb)) * w3;
  }
  float sums[3]; float vals[3] = {a0, a1, at};
  for (int r = 0; r < 3; ++r){
    float v = wave_sum(vals[r]);
    __syncthreads();
    if (ln == 0) lds[wv] = v;
    __syncthreads();
    sums[r] = lds[0] + lds[1] + lds[2] + lds[3];
  }
  if (tid == 0){
    const float b3 = g3b[0];
    const float g0 = l1_0 + sums[0] + b3;
    const float g1v = l1_1 + sums[1] + b3;
    const float gt = l1_t + sums[2] + b3;
    temb[b] = gamma0[0] + (gamma1[0] - gamma0[0]) * (gt - g0) / (g1v - g0);
  }
}

// ---------------- embedding: h0 = emb_in([species, t_emb, pdf_emb]) --------
__global__ __launch_bounds__(256) void k_embed(
    const float* __restrict__ xyz, const float* __restrict__ temb,
    const float* __restrict__ pdfe, const float* __restrict__ wi,
    const float* __restrict__ bi, float* __restrict__ h, float* __restrict__ x)
{
  int g = blockIdx.x * 256 + threadIdx.x;
  if (g >= BATCH*NATOMS*HF) return;
  int f = g & 31;
  int node = g >> 5;
  int b = node / NATOMS;
  float sp = xyz[node*4 + 3];
  const float* w = wi + f*12;
  float a = bi[f];
  a = fmaf(sp, w[0], a);
  a = fmaf(temb[b], w[1], a);
  const float* pe = pdfe + b*10;
#pragma unroll
  for (int p = 0; p < 10; ++p) a = fmaf(pe[p], w[2+p], a);
  h[node*32 + f] = a;
  if (f < 3) x[node*3 + f] = xyz[node*4 + f];
}

// ---------------- per-node precompute for layer 0 (LN + separable parts) ----
__global__ __launch_bounds__(256) void k_node(
    const float* __restrict__ hraw,
    const float* __restrict__ lnhg, const float* __restrict__ lnhb,
    const float* __restrict__ e1w, const float* __restrict__ e1b,
    const float* __restrict__ c1w, const float* __restrict__ c1b,
    float* __restrict__ hln, float* __restrict__ ue, float* __restrict__ uc,
    float* __restrict__ vep, float* __restrict__ vcp)
{
  int g = blockIdx.x * 256 + threadIdx.x;
  if (g >= BATCH*NATOMS*32) return;
  const int f = g & 31, node = g >> 5;
  const float* row = hraw + node*32;
  float hl[32];
  float m = 0.f;
#pragma unroll
  for (int k = 0; k < 32; ++k){ hl[k] = row[k]; m += hl[k]; }
  m *= (1.0f/32.0f);
  float v = 0.f;
#pragma unroll
  for (int k = 0; k < 32; ++k){ float d = hl[k]-m; v = fmaf(d, d, v); }
  float r = rsqrtf(v*(1.0f/32.0f) + 1e-5f);
#pragma unroll
  for (int k = 0; k < 32; ++k) hl[k] = fmaf((hl[k]-m)*r, lnhg[k], lnhb[k]);
  hln[node*32 + f] = hl[f];

  const float* we = e1w + f*66;
  float sv = e1b[f], su = 0.f;
#pragma unroll
  for (int k = 0; k < 32; ++k){ sv = fmaf(hl[k], we[k], sv); su = fmaf(hl[k], we[32+k], su); }
  vep[node*32 + f] = sv;
  ue [node*32 + f] = su;

  const float* wc = c1w + f*66;
  float cv = c1b[f], cu = 0.f;
#pragma unroll
  for (int k = 0; k < 32; ++k){ cv = fmaf(hl[k], wc[k], cv); cu = fmaf(hl[k], wc[32+k], cu); }
  vcp[node*32 + f] = cv;
  uc [node*32 + f] = cu;
}

// ---------------- pair kernel: block=(i, b, chunk), 128 threads -------------
// wave0 = edge chain for 64 j's; wave1 = cor chain for same 64 j's.
// m2/c2 never materialized: gate and c3 dots folded into the f-loop.
// Partial m_agg (32) and xc (3) written to global scratch; k_post finalizes.
// launch_bounds(128,6): VGPR ceiling ~85 — allocator should land ~55 with
// the array-free chains (round-2 lesson: never cap tighter than demand).
__global__ __launch_bounds__(128, 6) void k_pair(
    const float* __restrict__ xin, const float* __restrict__ xyz,
    const float* __restrict__ ue, const float* __restrict__ uc,
    const float* __restrict__ vep, const float* __restrict__ vcp,
    const float* __restrict__ e1w, const float* __restrict__ c1w,
    const float* __restrict__ e2w, const float* __restrict__ e2b,
    const float* __restrict__ eiw, const float* __restrict__ eib,
    const float* __restrict__ c2w, const float* __restrict__ c2b,
    const float* __restrict__ c3w, const float* __restrict__ c3b,
    float* __restrict__ pm, float* __restrict__ pxc)
{
  __shared__ float s_red[64][33];  // raw m2 per (j,f); stride 33 => 2-way (free)
  __shared__ float s_e[64];        // sigmoid gate per j

  const int i = blockIdx.x, b = blockIdx.y, chunk = blockIdx.z;
  const int lane = threadIdx.x & 63;
  const int isCor = threadIdx.x >> 6;
  const int j = chunk*64 + lane;
  const int base = b * NATOMS;

  // pair geometry (pre-LN x per reference)
  const float* xi_p = xin + (base + i)*3;
  const float* xj_p = xin + (base + j)*3;
  const float dfx = xi_p[0] - xj_p[0], dfy = xi_p[1] - xj_p[1], dfz = xi_p[2] - xj_p[2];
  const float d2 = dfx*dfx + dfy*dfy + dfz*dfz;
  const float dist = sqrtf(fmaxf(d2, 1e-12f));
  const float* x0i = xyz + (base + i)*4;
  const float* x0j = xyz + (base + j)*4;
  const float q0 = x0i[0]-x0j[0], q1 = x0i[1]-x0j[1], q2 = x0i[2]-x0j[2];
  const float d0 = sqrtf(fmaxf(q0*q0 + q1*q1 + q2*q2, 1e-12f));

  if (isCor == 0){
    // -------- edge chain --------
    float m1[32];
    {
      const float4* up = (const float4*)(ue + (size_t)(base + j)*32);
      const float* vp = vep + (base + i)*32;   // wave-uniform -> scalarized
#pragma unroll
      for (int q = 0; q < 8; ++q){
        float4 u4 = up[q];
        const int f0 = q*4;
        m1[f0+0] = silu_f(fmaf(d2, e1w[(f0+0)*66+64], fmaf(d0, e1w[(f0+0)*66+65], vp[f0+0]+u4.x)));
        m1[f0+1] = silu_f(fmaf(d2, e1w[(f0+1)*66+64], fmaf(d0, e1w[(f0+1)*66+65], vp[f0+1]+u4.y)));
        m1[f0+2] = silu_f(fmaf(d2, e1w[(f0+2)*66+64], fmaf(d0, e1w[(f0+2)*66+65], vp[f0+2]+u4.z)));
        m1[f0+3] = silu_f(fmaf(d2, e1w[(f0+3)*66+64], fmaf(d0, e1w[(f0+3)*66+65], vp[f0+3]+u4.w)));
      }
    }
    float eg = eib[0];
#pragma unroll
    for (int f = 0; f < 32; ++f){
      const float* w = e2w + f*32;
      float a = e2b[f];
#pragma unroll
      for (int k = 0; k < 32; ++k) a = fmaf(m1[k], w[k], a);
      float v = silu_f(a);
      eg = fmaf(v, eiw[f], eg);
      s_red[lane][f] = v;           // raw m2; gated during reduction
    }
    s_e[lane] = (i == j) ? 0.0f : sigmoid_f(eg);
  } else {
    // -------- coordinate chain --------
    float c1[32];
    {
      const float4* up = (const float4*)(uc + (size_t)(base + j)*32);
      const float* vp = vcp + (base + i)*32;
#pragma unroll
      for (int q = 0; q < 8; ++q){
        float4 u4 = up[q];
        const int f0 = q*4;
        c1[f0+0] = silu_f(fmaf(d2, c1w[(f0+0)*66+64], fmaf(d0, c1w[(f0+0)*66+65], vp[f0+0]+u4.x)));
        c1[f0+1] = silu_f(fmaf(d2, c1w[(f0+1)*66+64], fmaf(d0, c1w[(f0+1)*66+65], vp[f0+1]+u4.y)));
        c1[f0+2] = silu_f(fmaf(d2, c1w[(f0+2)*66+64], fmaf(d0, c1w[(f0+2)*66+65], vp[f0+2]+u4.z)));
        c1[f0+3] = silu_f(fmaf(d2, c1w[(f0+3)*66+64], fmaf(d0, c1w[(f0+3)*66+65], vp[f0+3]+u4.w)));
      }
    }
    float cwv = c3b[0];
#pragma unroll
    for (int f = 0; f < 32; ++f){
      const float* w = c2w + f*32;
      float a = c2b[f];
#pragma unroll
      for (int k = 0; k < 32; ++k) a = fmaf(c1[k], w[k], a);
      cwv = fmaf(silu_f(a), c3w[f], cwv);
    }
    const float s = cwv * fast_rcp(dist + 1.0f);
    float xc0 = wave_sum(s * dfx);
    float xc1 = wave_sum(s * dfy);
    float xc2 = wave_sum(s * dfz);
    if (lane == 0){
      float* o = pxc + ((size_t)(base + i)*3 + chunk)*3;
      o[0] = xc0; o[1] = xc1; o[2] = xc2;
    }
  }
  __syncthreads();

  if (isCor == 0){
    // gated j-reduction: lane handles f = lane&31 over half the j's
    const int f = lane & 31, jh = lane >> 5;
    float a = 0.f;
#pragma unroll
    for (int q = 0; q < 32; ++q){
      const int jj = jh*32 + q;
      a = fmaf(s_red[jj][f], s_e[jj], a);
    }
    a += __shfl_xor(a, 32);
    if (lane < 32) pm[((size_t)(base + i)*3 + chunk)*32 + f] = a;
  }
}

// ---------------- post: finalize layer l + precompute layer l+1 -------------
// block = 256 threads = 8 nodes x 32 f.
__global__ __launch_bounds__(256) void k_post(
    float* hln, const float* __restrict__ xin,
    const float* __restrict__ pm, const float* __restrict__ pxc,
    float* __restrict__ hout, float* __restrict__ xout,
    const float* __restrict__ n1w, const float* __restrict__ n1b,
    const float* __restrict__ n2w, const float* __restrict__ n2b,
    const float* __restrict__ lnxg, const float* __restrict__ lnxb,
    const float* __restrict__ lnhg_n, const float* __restrict__ lnhb_n,
    const float* __restrict__ e1w_n, const float* __restrict__ e1b_n,
    const float* __restrict__ c1w_n, const float* __restrict__ c1b_n,
    float* __restrict__ ue, float* __restrict__ uc,
    float* __restrict__ vep, float* __restrict__ vcp)
{
  __shared__ float s_hl[8][33];
  __shared__ float s_mg[8][33];
  __shared__ float s_n1[8][33];
  __shared__ float s_ho[8][33];

  const int tid = threadIdx.x;
  const int il = tid >> 5, f = tid & 31;
  const int node = blockIdx.x*8 + il;

  const float hlf = hln[node*32 + f];
  s_hl[il][f] = hlf;
  const float* pmn = pm + (size_t)node*96;
  s_mg[il][f] = pmn[f] + pmn[32 + f] + pmn[64 + f];
  __syncthreads();

  // node1
  float a = n1b[f];
  const float* w1 = n1w + f*64;
#pragma unroll
  for (int k = 0; k < 32; ++k) a = fmaf(s_hl[il][k], w1[k], a);
#pragma unroll
  for (int k = 0; k < 32; ++k) a = fmaf(s_mg[il][k], w1[32+k], a);
  s_n1[il][f] = silu_f(a);

  // x update (independent of node MLP)
  if (f < 3){
    const float* xr = xin + node*3;
    const float x0 = xr[0], x1 = xr[1], x2 = xr[2];
    const float mx = (x0 + x1 + x2) * (1.0f/3.0f);
    const float v0 = x0-mx, v1 = x1-mx, v2 = x2-mx;
    const float r = rsqrtf((v0*v0 + v1*v1 + v2*v2)*(1.0f/3.0f) + 1e-5f);
    const float xv = (f == 0) ? x0 : ((f == 1) ? x1 : x2);
    const float xl = fmaf((xv - mx)*r, lnxg[f], lnxb[f]);
    const float* pc = pxc + (size_t)node*9;
    xout[node*3 + f] = xl + pc[f] + pc[3 + f] + pc[6 + f];
  }
  __syncthreads();

  // node2 + residual
  float o = n2b[f];
  const float* w2 = n2w + f*32;
#pragma unroll
  for (int k = 0; k < 32; ++k) o = fmaf(s_n1[il][k], w2[k], o);
  const float ho = hlf + o;
  hout[node*32 + f] = ho;
  s_ho[il][f] = ho;
  __syncthreads();

  // LN of h_out row (next layer) + separable precompute
  float m = 0.f;
#pragma unroll
  for (int k = 0; k < 32; ++k) m += s_ho[il][k];
  m *= (1.0f/32.0f);
  float v = 0.f;
#pragma unroll
  for (int k = 0; k < 32; ++k){ float d = s_ho[il][k]-m; v = fmaf(d, d, v); }
  const float r = rsqrtf(v*(1.0f/32.0f) + 1e-5f);
  float hl[32];
#pragma unroll
  for (int k = 0; k < 32; ++k) hl[k] = fmaf((s_ho[il][k]-m)*r, lnhg_n[k], lnhb_n[k]);
  hln[node*32 + f] = hl[f];

  const float* we = e1w_n + f*66;
  float sv = e1b_n[f], su = 0.f;
#pragma unroll
  for (int k = 0; k < 32; ++k){ sv = fmaf(hl[k], we[k], sv); su = fmaf(hl[k], we[32+k], su); }
  vep[node*32 + f] = sv;
  ue [node*32 + f] = su;

  const float* wc = c1w_n + f*66;
  float cv = c1b_n[f], cu = 0.f;
#pragma unroll
  for (int k = 0; k < 32; ++k){ cv = fmaf(hl[k], wc[k], cv); cu = fmaf(hl[k], wc[32+k], cu); }
  vcp[node*32 + f] = cv;
  uc [node*32 + f] = cu;
}

// ---------------- epilogue: output heads --------------------------------
__global__ __launch_bounds__(256) void k_final(
    const float* __restrict__ hin, const float* __restrict__ xin,
    const float* __restrict__ xyz,
    const float* __restrict__ how, const float* __restrict__ hob,
    const float* __restrict__ xow, const float* __restrict__ xob,
    float* __restrict__ out)
{
  int g = blockIdx.x * 256 + threadIdx.x;
  if (g >= BATCH*NATOMS) return;
  const float* h = hin + g*32;
  float a = hob[0];
#pragma unroll
  for (int k = 0; k < 32; ++k) a = fmaf(h[k], how[k], a);
  const float* x = xin + g*3;
#pragma unroll
  for (int c = 0; c < 3; ++c){
    float o = xob[c];
    o = fmaf(x[0], xow[c*3+0], o);
    o = fmaf(x[1], xow[c*3+1], o);
    o = fmaf(x[2], xow[c*3+2], o);
    out[g*4 + c] = o - xyz[g*4 + c];
  }
  out[g*4 + 3] = a;
}

extern "C" void kernel_launch(void* const* d_in, const int* in_sizes, int n_in,
                              void* d_out, int out_size, void* d_ws, size_t ws_size,
                              hipStream_t stream)
{
  const float* xyz      = (const float*)d_in[0];
  const float* pdf      = (const float*)d_in[1];
  const float* t        = (const float*)d_in[2];
  const float* emb_in_w = (const float*)d_in[3];
  const float* emb_in_b = (const float*)d_in[4];
  const float* emb_out_w= (const float*)d_in[5];
  const float* emb_out_b= (const float*)d_in[6];
  const float* x_out_w  = (const float*)d_in[7];
  const float* x_out_b  = (const float*)d_in[8];
  const float* pdf_w    = (const float*)d_in[9];
  const float* pdf_b    = (const float*)d_in[10];
  const float* g1w      = (const float*)d_in[11];
  const float* g1b      = (const float*)d_in[12];
  const float* g2w      = (const float*)d_in[13];
  const float* g2b      = (const float*)d_in[14];
  const float* g3w      = (const float*)d_in[15];
  const float* g3b      = (const float*)d_in[16];
  const float* gamma0   = (const float*)d_in[17];
  const float* gamma1   = (const float*)d_in[18];
  const float* lnhg     = (const float*)d_in[19];
  const float* lnhb     = (const float*)d_in[20];
  const float* lnxg     = (const float*)d_in[21];
  const float* lnxb     = (const float*)d_in[22];
  const float* e1w      = (const float*)d_in[23];
  const float* e1b      = (const float*)d_in[24];
  const float* e2w      = (const float*)d_in[25];
  const float* e2b      = (const float*)d_in[26];
  const float* eiw      = (const float*)d_in[27];
  const float* eib      = (const float*)d_in[28];
  const float* n1w      = (const float*)d_in[29];
  const float* n1b      = (const float*)d_in[30];
  const float* n2w      = (const float*)d_in[31];
  const float* n2b      = (const float*)d_in[32];
  const float* c1w      = (const float*)d_in[33];
  const float* c1b      = (const float*)d_in[34];
  const float* c2w      = (const float*)d_in[35];
  const float* c2b      = (const float*)d_in[36];
  const float* c3w      = (const float*)d_in[37];
  const float* c3b      = (const float*)d_in[38];

  const int NTOT = BATCH*NATOMS;          // 1536 nodes
  float* ws   = (float*)d_ws;
  float* temb = ws;                        // 8
  float* pdfe = ws + 8;                    // 80 (pad to 96)
  float* h0   = ws + 96;                   // 49152
  float* hout = h0   + NTOT*32;            // 49152
  float* xb0  = hout + NTOT*32;            // 4608
  float* xb1  = xb0  + NTOT*3;             // 4608
  float* hln  = xb1  + NTOT*3;             // 49152
  float* ue   = hln  + NTOT*32;
  float* uc   = ue   + NTOT*32;
  float* vep  = uc   + NTOT*32;
  float* vcp  = vep  + NTOT*32;
  float* pm   = vcp  + NTOT*32;            // 1536*3*32 = 147456
  float* pxc  = pm   + NTOT*96;            // 1536*9 = 13824

  k_prelude<<<88, 256, 0, stream>>>(pdf, t, pdf_w, pdf_b,
      g1w, g1b, g2w, g2b, g3w, g3b, gamma0, gamma1, temb, pdfe);
  k_embed<<<(NTOT*HF + 255)/256, 256, 0, stream>>>(
      xyz, temb, pdfe, emb_in_w, emb_in_b, h0, xb0);
  k_node<<<(NTOT*32 + 255)/256, 256, 0, stream>>>(
      h0, lnhg, lnhb, e1w, e1b, c1w, c1b, hln, ue, uc, vep, vcp);

  const float* xcur = xb0; float* xnext = xb1;
  for (int l = 0; l < 4; ++l){
    const int n = (l < 3) ? (l + 1) : 3;   // next-layer weights for precompute
    k_pair<<<dim3(NATOMS, BATCH, 3), 128, 0, stream>>>(
        xcur, xyz, ue, uc, vep, vcp,
        e1w + l*2112, c1w + l*2112,
        e2w + l*1024, e2b + l*32, eiw + l*32, eib + l,
        c2w + l*1024, c2b + l*32, c3w + l*32, c3b + l,
        pm, pxc);
    k_post<<<NTOT/8, 256, 0, stream>>>(
        hln, xcur, pm, pxc, hout, xnext,
        n1w + l*2048, n1b + l*32, n2w + l*1024, n2b + l*32,
        lnxg + l*3, lnxb + l*3,
        lnhg + n*32, lnhb + n*32, e1w + n*2112, e1b + n*32,
        c1w + n*2112, c1b + n*32,
        ue, uc, vep, vcp);
    const float* tx = xcur; xcur = xnext; xnext = (float*)tx;
  }

  k_final<<<(NTOT + 255)/256, 256, 0, stream>>>(
      hout, xcur, xyz, emb_out_w, emb_out_b, x_out_w, x_out_b, (float*)d_out);
}

// Round 6
// 336.465 us; speedup vs baseline: 1.5984x; 1.5984x over previous
//
#include <hip/hip_runtime.h>
#include <math.h>

#define BATCH 8
#define NATOMS 192
#define HF 32

__device__ __forceinline__ float fast_rcp(float x){ return __builtin_amdgcn_rcpf(x); }
__device__ __forceinline__ float sigmoid_f(float x){ return fast_rcp(1.0f+__expf(-x)); }
__device__ __forceinline__ float silu_f(float x){ return x*fast_rcp(1.0f+__expf(-x)); }
__device__ __forceinline__ float softplus_f(float x){ return fmaxf(x,0.0f)+log1pf(expf(-fabsf(x))); }

__device__ __forceinline__ float wave_sum(float v){
  v += __shfl_xor(v, 1);
  v += __shfl_xor(v, 2);
  v += __shfl_xor(v, 4);
  v += __shfl_xor(v, 8);
  v += __shfl_xor(v, 16);
  v += __shfl_xor(v, 32);
  return v;
}

// ---------------- prelude: blocks 0..79 = pdf dot (b,o); 80..87 = gamma(b) --
__global__ __launch_bounds__(256) void k_prelude(
    const float* __restrict__ pdf, const float* __restrict__ t,
    const float* __restrict__ pdf_w, const float* __restrict__ pdf_b,
    const float* __restrict__ g1w, const float* __restrict__ g1b,
    const float* __restrict__ g2w, const float* __restrict__ g2b,
    const float* __restrict__ g3w, const float* __restrict__ g3b,
    const float* __restrict__ gamma0, const float* __restrict__ gamma1,
    float* __restrict__ temb, float* __restrict__ pdfe)
{
  __shared__ float lds[4];
  const int bx = blockIdx.x, tid = threadIdx.x;
  const int wv = tid >> 6, ln = tid & 63;

  if (bx < 80){
    const int b = bx / 10, o = bx % 10;
    const float* pb = pdf + b*3000;
    const float* wb = pdf_w + o*3000;
    float p = 0.f;
    for (int k = tid; k < 3000; k += 256) p = fmaf(pb[k], wb[k], p);
    p = wave_sum(p);
    if (ln == 0) lds[wv] = p;
    __syncthreads();
    if (tid == 0) pdfe[b*10 + o] = lds[0] + lds[1] + lds[2] + lds[3] + pdf_b[o];
    return;
  }
  const int b = bx - 80;
  const float w1 = softplus_f(g1w[0]);
  const float b1 = g1b[0];
  const float tn = t[b] * (1.0f/1000.0f);
  const float l1_0 = b1;
  const float l1_1 = w1 + b1;
  const float l1_t = fmaf(w1, tn, b1);
  float a0 = 0.f, a1 = 0.f, at = 0.f;
  for (int k = tid; k < 1024; k += 256){
    float w2 = softplus_f(g2w[k]);
    float bb = g2b[k];
    float w3 = softplus_f(g3w[k]);
    a0 += sigmoid_f(fmaf(w2, l1_0, bb)) * w3;
    a1 += sigmoid_f(fmaf(w2, l1_1, bb)) * w3;
    at += sigmoid_f(fmaf(w2, l1_t, bb)) * w3;
  }
  float sums[3]; float vals[3] = {a0, a1, at};
  for (int r = 0; r < 3; ++r){
    float v = wave_sum(vals[r]);
    __syncthreads();
    if (ln == 0) lds[wv] = v;
    __syncthreads();
    sums[r] = lds[0] + lds[1] + lds[2] + lds[3];
  }
  if (tid == 0){
    const float b3 = g3b[0];
    const float g0 = l1_0 + sums[0] + b3;
    const float g1v = l1_1 + sums[1] + b3;
    const float gt = l1_t + sums[2] + b3;
    temb[b] = gamma0[0] + (gamma1[0] - gamma0[0]) * (gt - g0) / (g1v - g0);
  }
}

// ---------------- embedding: h0 = emb_in([species, t_emb, pdf_emb]) --------
__global__ __launch_bounds__(256) void k_embed(
    const float* __restrict__ xyz, const float* __restrict__ temb,
    const float* __restrict__ pdfe, const float* __restrict__ wi,
    const float* __restrict__ bi, float* __restrict__ h, float* __restrict__ x)
{
  int g = blockIdx.x * 256 + threadIdx.x;
  if (g >= BATCH*NATOMS*HF) return;
  int f = g & 31;
  int node = g >> 5;
  int b = node / NATOMS;
  float sp = xyz[node*4 + 3];
  const float* w = wi + f*12;
  float a = bi[f];
  a = fmaf(sp, w[0], a);
  a = fmaf(temb[b], w[1], a);
  const float* pe = pdfe + b*10;
#pragma unroll
  for (int p = 0; p < 10; ++p) a = fmaf(pe[p], w[2+p], a);
  h[node*32 + f] = a;
  if (f < 3) x[node*3 + f] = xyz[node*4 + f];
}

// ---------------- per-node precompute for layer 0 (LN + separable parts) ----
__global__ __launch_bounds__(256) void k_node(
    const float* __restrict__ hraw,
    const float* __restrict__ lnhg, const float* __restrict__ lnhb,
    const float* __restrict__ e1w, const float* __restrict__ e1b,
    const float* __restrict__ c1w, const float* __restrict__ c1b,
    float* __restrict__ hln, float* __restrict__ ue, float* __restrict__ uc,
    float* __restrict__ vep, float* __restrict__ vcp)
{
  int g = blockIdx.x * 256 + threadIdx.x;
  if (g >= BATCH*NATOMS*32) return;
  const int f = g & 31, node = g >> 5;
  const float* row = hraw + node*32;
  float hl[32];
  float m = 0.f;
#pragma unroll
  for (int k = 0; k < 32; ++k){ hl[k] = row[k]; m += hl[k]; }
  m *= (1.0f/32.0f);
  float v = 0.f;
#pragma unroll
  for (int k = 0; k < 32; ++k){ float d = hl[k]-m; v = fmaf(d, d, v); }
  float r = rsqrtf(v*(1.0f/32.0f) + 1e-5f);
#pragma unroll
  for (int k = 0; k < 32; ++k) hl[k] = fmaf((hl[k]-m)*r, lnhg[k], lnhb[k]);
  hln[node*32 + f] = hl[f];

  const float* we = e1w + f*66;
  float sv = e1b[f], su = 0.f;
#pragma unroll
  for (int k = 0; k < 32; ++k){ sv = fmaf(hl[k], we[k], sv); su = fmaf(hl[k], we[32+k], su); }
  vep[node*32 + f] = sv;
  ue [node*32 + f] = su;

  const float* wc = c1w + f*66;
  float cv = c1b[f], cu = 0.f;
#pragma unroll
  for (int k = 0; k < 32; ++k){ cv = fmaf(hl[k], wc[k], cv); cu = fmaf(hl[k], wc[32+k], cu); }
  vcp[node*32 + f] = cv;
  uc [node*32 + f] = cu;
}

// ---------------- pair kernel: block=(i, b, chunk), 128 threads -------------
// wave0 = edge chain for 64 j's; wave1 = cor chain for same 64 j's.
// m2/c2 never materialized: gate and c3 dots folded into the f-loop.
// Partial m_agg (32) and xc (3) written to global scratch; k_post finalizes.
// launch_bounds(128,4): VGPR ceiling 128 vs demand ~90. Round-5 lesson:
// (128,6) capped at 85 < demand -> allocator spilled m1/c1 (28 MB scratch
// writes, VGPR collapsed to 40). NEVER cap below demand.
__global__ __launch_bounds__(128, 4) void k_pair(
    const float* __restrict__ xin, const float* __restrict__ xyz,
    const float* __restrict__ ue, const float* __restrict__ uc,
    const float* __restrict__ vep, const float* __restrict__ vcp,
    const float* __restrict__ e1w, const float* __restrict__ c1w,
    const float* __restrict__ e2w, const float* __restrict__ e2b,
    const float* __restrict__ eiw, const float* __restrict__ eib,
    const float* __restrict__ c2w, const float* __restrict__ c2b,
    const float* __restrict__ c3w, const float* __restrict__ c3b,
    float* __restrict__ pm, float* __restrict__ pxc)
{
  __shared__ float s_red[64][33];  // raw m2 per (j,f); stride 33 => 2-way (free)
  __shared__ float s_e[64];        // sigmoid gate per j
  __shared__ float s_part[4][33];  // reduction partials

  const int i = blockIdx.x, b = blockIdx.y, chunk = blockIdx.z;
  const int tid = threadIdx.x;
  const int lane = tid & 63;
  const int isCor = tid >> 6;
  const int j = chunk*64 + lane;
  const int base = b * NATOMS;

  // pair geometry (pre-LN x per reference)
  const float* xi_p = xin + (base + i)*3;
  const float* xj_p = xin + (base + j)*3;
  const float dfx = xi_p[0] - xj_p[0], dfy = xi_p[1] - xj_p[1], dfz = xi_p[2] - xj_p[2];
  const float d2 = dfx*dfx + dfy*dfy + dfz*dfz;
  const float dist = sqrtf(fmaxf(d2, 1e-12f));
  const float* x0i = xyz + (base + i)*4;
  const float* x0j = xyz + (base + j)*4;
  const float q0 = x0i[0]-x0j[0], q1 = x0i[1]-x0j[1], q2 = x0i[2]-x0j[2];
  const float d0 = sqrtf(fmaxf(q0*q0 + q1*q1 + q2*q2, 1e-12f));

  if (isCor == 0){
    // -------- edge chain --------
    float m1[32];
    {
      const float4* up = (const float4*)(ue + (size_t)(base + j)*32);
      const float* vp = vep + (base + i)*32;   // wave-uniform -> scalarized
#pragma unroll
      for (int q = 0; q < 8; ++q){
        float4 u4 = up[q];
        const int f0 = q*4;
        m1[f0+0] = silu_f(fmaf(d2, e1w[(f0+0)*66+64], fmaf(d0, e1w[(f0+0)*66+65], vp[f0+0]+u4.x)));
        m1[f0+1] = silu_f(fmaf(d2, e1w[(f0+1)*66+64], fmaf(d0, e1w[(f0+1)*66+65], vp[f0+1]+u4.y)));
        m1[f0+2] = silu_f(fmaf(d2, e1w[(f0+2)*66+64], fmaf(d0, e1w[(f0+2)*66+65], vp[f0+2]+u4.z)));
        m1[f0+3] = silu_f(fmaf(d2, e1w[(f0+3)*66+64], fmaf(d0, e1w[(f0+3)*66+65], vp[f0+3]+u4.w)));
      }
    }
    float eg = eib[0];
#pragma unroll
    for (int f = 0; f < 32; ++f){
      const float* w = e2w + f*32;
      float a = e2b[f];
#pragma unroll
      for (int k = 0; k < 32; ++k) a = fmaf(m1[k], w[k], a);
      float v = silu_f(a);
      eg = fmaf(v, eiw[f], eg);
      s_red[lane][f] = v;           // raw m2; gated during reduction
    }
    s_e[lane] = (i == j) ? 0.0f : sigmoid_f(eg);
  } else {
    // -------- coordinate chain --------
    float c1[32];
    {
      const float4* up = (const float4*)(uc + (size_t)(base + j)*32);
      const float* vp = vcp + (base + i)*32;
#pragma unroll
      for (int q = 0; q < 8; ++q){
        float4 u4 = up[q];
        const int f0 = q*4;
        c1[f0+0] = silu_f(fmaf(d2, c1w[(f0+0)*66+64], fmaf(d0, c1w[(f0+0)*66+65], vp[f0+0]+u4.x)));
        c1[f0+1] = silu_f(fmaf(d2, c1w[(f0+1)*66+64], fmaf(d0, c1w[(f0+1)*66+65], vp[f0+1]+u4.y)));
        c1[f0+2] = silu_f(fmaf(d2, c1w[(f0+2)*66+64], fmaf(d0, c1w[(f0+2)*66+65], vp[f0+2]+u4.z)));
        c1[f0+3] = silu_f(fmaf(d2, c1w[(f0+3)*66+64], fmaf(d0, c1w[(f0+3)*66+65], vp[f0+3]+u4.w)));
      }
    }
    float cwv = c3b[0];
#pragma unroll
    for (int f = 0; f < 32; ++f){
      const float* w = c2w + f*32;
      float a = c2b[f];
#pragma unroll
      for (int k = 0; k < 32; ++k) a = fmaf(c1[k], w[k], a);
      cwv = fmaf(silu_f(a), c3w[f], cwv);
    }
    const float s = cwv * fast_rcp(dist + 1.0f);
    float xc0 = wave_sum(s * dfx);
    float xc1 = wave_sum(s * dfy);
    float xc2 = wave_sum(s * dfz);
    if (lane == 0){
      float* o = pxc + ((size_t)(base + i)*3 + chunk)*3;
      o[0] = xc0; o[1] = xc1; o[2] = xc2;
    }
  }
  __syncthreads();

  // gated j-reduction across ALL 128 threads: f = tid&31, quarter = tid>>5
  {
    const int f = tid & 31, qh = tid >> 5;
    float a = 0.f;
#pragma unroll
    for (int q = 0; q < 16; ++q){
      const int jj = qh*16 + q;
      a = fmaf(s_red[jj][f], s_e[jj], a);
    }
    s_part[qh][f] = a;
  }
  __syncthreads();
  if (tid < 32){
    pm[((size_t)(base + i)*3 + chunk)*32 + tid] =
        s_part[0][tid] + s_part[1][tid] + s_part[2][tid] + s_part[3][tid];
  }
}

// ---------------- post: finalize layer l + precompute layer l+1 -------------
// block = 256 threads = 8 nodes x 32 f.
__global__ __launch_bounds__(256) void k_post(
    float* hln, const float* __restrict__ xin,
    const float* __restrict__ pm, const float* __restrict__ pxc,
    float* __restrict__ hout, float* __restrict__ xout,
    const float* __restrict__ n1w, const float* __restrict__ n1b,
    const float* __restrict__ n2w, const float* __restrict__ n2b,
    const float* __restrict__ lnxg, const float* __restrict__ lnxb,
    const float* __restrict__ lnhg_n, const float* __restrict__ lnhb_n,
    const float* __restrict__ e1w_n, const float* __restrict__ e1b_n,
    const float* __restrict__ c1w_n, const float* __restrict__ c1b_n,
    float* __restrict__ ue, float* __restrict__ uc,
    float* __restrict__ vep, float* __restrict__ vcp)
{
  __shared__ float s_hl[8][33];
  __shared__ float s_mg[8][33];
  __shared__ float s_n1[8][33];
  __shared__ float s_ho[8][33];

  const int tid = threadIdx.x;
  const int il = tid >> 5, f = tid & 31;
  const int node = blockIdx.x*8 + il;

  const float hlf = hln[node*32 + f];
  s_hl[il][f] = hlf;
  const float* pmn = pm + (size_t)node*96;
  s_mg[il][f] = pmn[f] + pmn[32 + f] + pmn[64 + f];
  __syncthreads();

  // node1
  float a = n1b[f];
  const float* w1 = n1w + f*64;
#pragma unroll
  for (int k = 0; k < 32; ++k) a = fmaf(s_hl[il][k], w1[k], a);
#pragma unroll
  for (int k = 0; k < 32; ++k) a = fmaf(s_mg[il][k], w1[32+k], a);
  s_n1[il][f] = silu_f(a);

  // x update (independent of node MLP)
  if (f < 3){
    const float* xr = xin + node*3;
    const float x0 = xr[0], x1 = xr[1], x2 = xr[2];
    const float mx = (x0 + x1 + x2) * (1.0f/3.0f);
    const float v0 = x0-mx, v1 = x1-mx, v2 = x2-mx;
    const float r = rsqrtf((v0*v0 + v1*v1 + v2*v2)*(1.0f/3.0f) + 1e-5f);
    const float xv = (f == 0) ? x0 : ((f == 1) ? x1 : x2);
    const float xl = fmaf((xv - mx)*r, lnxg[f], lnxb[f]);
    const float* pc = pxc + (size_t)node*9;
    xout[node*3 + f] = xl + pc[f] + pc[3 + f] + pc[6 + f];
  }
  __syncthreads();

  // node2 + residual
  float o = n2b[f];
  const float* w2 = n2w + f*32;
#pragma unroll
  for (int k = 0; k < 32; ++k) o = fmaf(s_n1[il][k], w2[k], o);
  const float ho = hlf + o;
  hout[node*32 + f] = ho;
  s_ho[il][f] = ho;
  __syncthreads();

  // LN of h_out row (next layer) + separable precompute
  float m = 0.f;
#pragma unroll
  for (int k = 0; k < 32; ++k) m += s_ho[il][k];
  m *= (1.0f/32.0f);
  float v = 0.f;
#pragma unroll
  for (int k = 0; k < 32; ++k){ float d = s_ho[il][k]-m; v = fmaf(d, d, v); }
  const float r = rsqrtf(v*(1.0f/32.0f) + 1e-5f);
  float hl[32];
#pragma unroll
  for (int k = 0; k < 32; ++k) hl[k] = fmaf((s_ho[il][k]-m)*r, lnhg_n[k], lnhb_n[k]);
  hln[node*32 + f] = hl[f];

  const float* we = e1w_n + f*66;
  float sv = e1b_n[f], su = 0.f;
#pragma unroll
  for (int k = 0; k < 32; ++k){ sv = fmaf(hl[k], we[k], sv); su = fmaf(hl[k], we[32+k], su); }
  vep[node*32 + f] = sv;
  ue [node*32 + f] = su;

  const float* wc = c1w_n + f*66;
  float cv = c1b_n[f], cu = 0.f;
#pragma unroll
  for (int k = 0; k < 32; ++k){ cv = fmaf(hl[k], wc[k], cv); cu = fmaf(hl[k], wc[32+k], cu); }
  vcp[node*32 + f] = cv;
  uc [node*32 + f] = cu;
}

// ---------------- epilogue: output heads --------------------------------
__global__ __launch_bounds__(256) void k_final(
    const float* __restrict__ hin, const float* __restrict__ xin,
    const float* __restrict__ xyz,
    const float* __restrict__ how, const float* __restrict__ hob,
    const float* __restrict__ xow, const float* __restrict__ xob,
    float* __restrict__ out)
{
  int g = blockIdx.x * 256 + threadIdx.x;
  if (g >= BATCH*NATOMS) return;
  const float* h = hin + g*32;
  float a = hob[0];
#pragma unroll
  for (int k = 0; k < 32; ++k) a = fmaf(h[k], how[k], a);
  const float* x = xin + g*3;
#pragma unroll
  for (int c = 0; c < 3; ++c){
    float o = xob[c];
    o = fmaf(x[0], xow[c*3+0], o);
    o = fmaf(x[1], xow[c*3+1], o);
    o = fmaf(x[2], xow[c*3+2], o);
    out[g*4 + c] = o - xyz[g*4 + c];
  }
  out[g*4 + 3] = a;
}

extern "C" void kernel_launch(void* const* d_in, const int* in_sizes, int n_in,
                              void* d_out, int out_size, void* d_ws, size_t ws_size,
                              hipStream_t stream)
{
  const float* xyz      = (const float*)d_in[0];
  const float* pdf      = (const float*)d_in[1];
  const float* t        = (const float*)d_in[2];
  const float* emb_in_w = (const float*)d_in[3];
  const float* emb_in_b = (const float*)d_in[4];
  const float* emb_out_w= (const float*)d_in[5];
  const float* emb_out_b= (const float*)d_in[6];
  const float* x_out_w  = (const float*)d_in[7];
  const float* x_out_b  = (const float*)d_in[8];
  const float* pdf_w    = (const float*)d_in[9];
  const float* pdf_b    = (const float*)d_in[10];
  const float* g1w      = (const float*)d_in[11];
  const float* g1b      = (const float*)d_in[12];
  const float* g2w      = (const float*)d_in[13];
  const float* g2b      = (const float*)d_in[14];
  const float* g3w      = (const float*)d_in[15];
  const float* g3b      = (const float*)d_in[16];
  const float* gamma0   = (const float*)d_in[17];
  const float* gamma1   = (const float*)d_in[18];
  const float* lnhg     = (const float*)d_in[19];
  const float* lnhb     = (const float*)d_in[20];
  const float* lnxg     = (const float*)d_in[21];
  const float* lnxb     = (const float*)d_in[22];
  const float* e1w      = (const float*)d_in[23];
  const float* e1b      = (const float*)d_in[24];
  const float* e2w      = (const float*)d_in[25];
  const float* e2b      = (const float*)d_in[26];
  const float* eiw      = (const float*)d_in[27];
  const float* eib      = (const float*)d_in[28];
  const float* n1w      = (const float*)d_in[29];
  const float* n1b      = (const float*)d_in[30];
  const float* n2w      = (const float*)d_in[31];
  const float* n2b      = (const float*)d_in[32];
  const float* c1w      = (const float*)d_in[33];
  const float* c1b      = (const float*)d_in[34];
  const float* c2w      = (const float*)d_in[35];
  const float* c2b      = (const float*)d_in[36];
  const float* c3w      = (const float*)d_in[37];
  const float* c3b      = (const float*)d_in[38];

  const int NTOT = BATCH*NATOMS;          // 1536 nodes
  float* ws   = (float*)d_ws;
  float* temb = ws;                        // 8
  float* pdfe = ws + 8;                    // 80 (pad to 96)
  float* h0   = ws + 96;                   // 49152
  float* hout = h0   + NTOT*32;            // 49152
  float* xb0  = hout + NTOT*32;            // 4608
  float* xb1  = xb0  + NTOT*3;             // 4608
  float* hln  = xb1  + NTOT*3;             // 49152
  float* ue   = hln  + NTOT*32;
  float* uc   = ue   + NTOT*32;
  float* vep  = uc   + NTOT*32;
  float* vcp  = vep  + NTOT*32;
  float* pm   = vcp  + NTOT*32;            // 1536*96
  float* pxc  = pm   + NTOT*96;            // 1536*9

  k_prelude<<<88, 256, 0, stream>>>(pdf, t, pdf_w, pdf_b,
      g1w, g1b, g2w, g2b, g3w, g3b, gamma0, gamma1, temb, pdfe);
  k_embed<<<(NTOT*HF + 255)/256, 256, 0, stream>>>(
      xyz, temb, pdfe, emb_in_w, emb_in_b, h0, xb0);
  k_node<<<(NTOT*32 + 255)/256, 256, 0, stream>>>(
      h0, lnhg, lnhb, e1w, e1b, c1w, c1b, hln, ue, uc, vep, vcp);

  const float* xcur = xb0; float* xnext = xb1;
  for (int l = 0; l < 4; ++l){
    const int n = (l < 3) ? (l + 1) : 3;   // next-layer weights for precompute
    k_pair<<<dim3(NATOMS, BATCH, 3), 128, 0, stream>>>(
        xcur, xyz, ue, uc, vep, vcp,
        e1w + l*2112, c1w + l*2112,
        e2w + l*1024, e2b + l*32, eiw + l*32, eib + l,
        c2w + l*1024, c2b + l*32, c3w + l*32, c3b + l,
        pm, pxc);
    k_post<<<NTOT/8, 256, 0, stream>>>(
        hln, xcur, pm, pxc, hout, xnext,
        n1w + l*2048, n1b + l*32, n2w + l*1024, n2b + l*32,
        lnxg + l*3, lnxb + l*3,
        lnhg + n*32, lnhb + n*32, e1w + n*2112, e1b + n*32,
        c1w + n*2112, c1b + n*32,
        ue, uc, vep, vcp);
    const float* tx = xcur; xcur = xnext; xnext = (float*)tx;
  }

  k_final<<<(NTOT + 255)/256, 256, 0, stream>>>(
      hout, xcur, xyz, emb_out_w, emb_out_b, x_out_w, x_out_b, (float*)d_out);
}

// Round 7
// 274.897 us; speedup vs baseline: 1.9564x; 1.2240x over previous
//
#include <hip/hip_runtime.h>
#include <hip/hip_bf16.h>
#include <math.h>

#define BATCH 8
#define NATOMS 192
#define HF 32

using short8 = __attribute__((ext_vector_type(8))) short;
using f32x4  = __attribute__((ext_vector_type(4))) float;

__device__ __forceinline__ float fast_rcp(float x){ return __builtin_amdgcn_rcpf(x); }
__device__ __forceinline__ float sigmoid_f(float x){ return fast_rcp(1.0f+__expf(-x)); }
__device__ __forceinline__ float silu_f(float x){ return x*fast_rcp(1.0f+__expf(-x)); }
__device__ __forceinline__ float softplus_f(float x){ return fmaxf(x,0.0f)+log1pf(expf(-fabsf(x))); }
__device__ __forceinline__ unsigned short f2bf(float x){
  __hip_bfloat16 h = __float2bfloat16(x);
  return __builtin_bit_cast(unsigned short, h);
}

__device__ __forceinline__ float wave_sum(float v){
  v += __shfl_xor(v, 1);
  v += __shfl_xor(v, 2);
  v += __shfl_xor(v, 4);
  v += __shfl_xor(v, 8);
  v += __shfl_xor(v, 16);
  v += __shfl_xor(v, 32);
  return v;
}

// ---------------- prelude: blocks 0..79 = pdf dot (b,o); 80..87 = gamma(b) --
__global__ __launch_bounds__(256) void k_prelude(
    const float* __restrict__ pdf, const float* __restrict__ t,
    const float* __restrict__ pdf_w, const float* __restrict__ pdf_b,
    const float* __restrict__ g1w, const float* __restrict__ g1b,
    const float* __restrict__ g2w, const float* __restrict__ g2b,
    const float* __restrict__ g3w, const float* __restrict__ g3b,
    const float* __restrict__ gamma0, const float* __restrict__ gamma1,
    float* __restrict__ temb, float* __restrict__ pdfe)
{
  __shared__ float lds[4];
  const int bx = blockIdx.x, tid = threadIdx.x;
  const int wv = tid >> 6, ln = tid & 63;

  if (bx < 80){
    const int b = bx / 10, o = bx % 10;
    const float* pb = pdf + b*3000;
    const float* wb = pdf_w + o*3000;
    float p = 0.f;
    for (int k = tid; k < 3000; k += 256) p = fmaf(pb[k], wb[k], p);
    p = wave_sum(p);
    if (ln == 0) lds[wv] = p;
    __syncthreads();
    if (tid == 0) pdfe[b*10 + o] = lds[0] + lds[1] + lds[2] + lds[3] + pdf_b[o];
    return;
  }
  const int b = bx - 80;
  const float w1 = softplus_f(g1w[0]);
  const float b1 = g1b[0];
  const float tn = t[b] * (1.0f/1000.0f);
  const float l1_0 = b1;
  const float l1_1 = w1 + b1;
  const float l1_t = fmaf(w1, tn, b1);
  float a0 = 0.f, a1 = 0.f, at = 0.f;
  for (int k = tid; k < 1024; k += 256){
    float w2 = softplus_f(g2w[k]);
    float bb = g2b[k];
    float w3 = softplus_f(g3w[k]);
    a0 += sigmoid_f(fmaf(w2, l1_0, bb)) * w3;
    a1 += sigmoid_f(fmaf(w2, l1_1, bb)) * w3;
    at += sigmoid_f(fmaf(w2, l1_t, bb)) * w3;
  }
  float sums[3]; float vals[3] = {a0, a1, at};
  for (int r = 0; r < 3; ++r){
    float v = wave_sum(vals[r]);
    __syncthreads();
    if (ln == 0) lds[wv] = v;
    __syncthreads();
    sums[r] = lds[0] + lds[1] + lds[2] + lds[3];
  }
  if (tid == 0){
    const float b3 = g3b[0];
    const float g0 = l1_0 + sums[0] + b3;
    const float g1v = l1_1 + sums[1] + b3;
    const float gt = l1_t + sums[2] + b3;
    temb[b] = gamma0[0] + (gamma1[0] - gamma0[0]) * (gt - g0) / (g1v - g0);
  }
}

// ---------------- embedding: h0 = emb_in([species, t_emb, pdf_emb]) --------
__global__ __launch_bounds__(256) void k_embed(
    const float* __restrict__ xyz, const float* __restrict__ temb,
    const float* __restrict__ pdfe, const float* __restrict__ wi,
    const float* __restrict__ bi, float* __restrict__ h, float* __restrict__ x)
{
  int g = blockIdx.x * 256 + threadIdx.x;
  if (g >= BATCH*NATOMS*HF) return;
  int f = g & 31;
  int node = g >> 5;
  int b = node / NATOMS;
  float sp = xyz[node*4 + 3];
  const float* w = wi + f*12;
  float a = bi[f];
  a = fmaf(sp, w[0], a);
  a = fmaf(temb[b], w[1], a);
  const float* pe = pdfe + b*10;
#pragma unroll
  for (int p = 0; p < 10; ++p) a = fmaf(pe[p], w[2+p], a);
  h[node*32 + f] = a;
  if (f < 3) x[node*3 + f] = xyz[node*4 + f];
}

// ---------------- weight prep (once): e2w/c2w (all 4 layers) -> bf16 -------
__global__ __launch_bounds__(256) void k_wprep(
    const float* __restrict__ e2w, const float* __restrict__ c2w,
    unsigned short* __restrict__ e2wb, unsigned short* __restrict__ c2wb)
{
  int g = blockIdx.x*256 + threadIdx.x;
  if (g < 4096){
    e2wb[g] = f2bf(e2w[g]);
    c2wb[g] = f2bf(c2w[g]);
  }
}

// ---------------- per-node precompute for layer 0 (LN + separable parts) ----
__global__ __launch_bounds__(256) void k_node(
    const float* __restrict__ hraw,
    const float* __restrict__ lnhg, const float* __restrict__ lnhb,
    const float* __restrict__ e1w, const float* __restrict__ e1b,
    const float* __restrict__ c1w, const float* __restrict__ c1b,
    float* __restrict__ hln, float* __restrict__ ue, float* __restrict__ uc,
    float* __restrict__ vep, float* __restrict__ vcp)
{
  int g = blockIdx.x * 256 + threadIdx.x;
  if (g >= BATCH*NATOMS*32) return;
  const int f = g & 31, node = g >> 5;
  const float* row = hraw + node*32;
  float hl[32];
  float m = 0.f;
#pragma unroll
  for (int k = 0; k < 32; ++k){ hl[k] = row[k]; m += hl[k]; }
  m *= (1.0f/32.0f);
  float v = 0.f;
#pragma unroll
  for (int k = 0; k < 32; ++k){ float d = hl[k]-m; v = fmaf(d, d, v); }
  float r = rsqrtf(v*(1.0f/32.0f) + 1e-5f);
#pragma unroll
  for (int k = 0; k < 32; ++k) hl[k] = fmaf((hl[k]-m)*r, lnhg[k], lnhb[k]);
  hln[node*32 + f] = hl[f];

  const float* we = e1w + f*66;
  float sv = e1b[f], su = 0.f;
#pragma unroll
  for (int k = 0; k < 32; ++k){ sv = fmaf(hl[k], we[k], sv); su = fmaf(hl[k], we[32+k], su); }
  vep[node*32 + f] = sv;
  ue [node*32 + f] = su;

  const float* wc = c1w + f*66;
  float cv = c1b[f], cu = 0.f;
#pragma unroll
  for (int k = 0; k < 32; ++k){ cv = fmaf(hl[k], wc[k], cv); cu = fmaf(hl[k], wc[32+k], cu); }
  vcp[node*32 + f] = cv;
  uc [node*32 + f] = cu;
}

// ---------------- pair kernel (MFMA): block=(i, b, chunk), 128 threads ------
// Phase 0: tid<64 computes pair geometry -> s_geo; tid>=64 stages bf16
//          e2/c2 weights to LDS as B^T rows [f][k] (verified b_frag layout).
// Phase 1: all threads compute m1/c1 (separable edg1/cor1) fp32 -> bf16 LDS
//          [j][40] padded rows.
// Phase 2: wave0 = edge (4 jt x 2 ft mfma_16x16x32_bf16 + gate/m_agg),
//          wave1 = cor (mfma + c3 dot + xc). C layout: f=lane&15(+16*ft),
//          j=jt*16+quad*4+reg [m89/m91]. No barriers after phase 1.
// launch_bounds(128,3): cap ~170 vs demand ~100 (R2/R5 lesson: loose cap).
__global__ __launch_bounds__(128, 3) void k_pair(
    const float* __restrict__ xin, const float* __restrict__ xyz,
    const float* __restrict__ ue, const float* __restrict__ uc,
    const float* __restrict__ vep, const float* __restrict__ vcp,
    const float* __restrict__ e1w, const float* __restrict__ c1w,
    const unsigned short* __restrict__ e2wb, const unsigned short* __restrict__ c2wb,
    const float* __restrict__ e2b, const float* __restrict__ eiw,
    const float* __restrict__ eib,
    const float* __restrict__ c2b, const float* __restrict__ c3w,
    const float* __restrict__ c3b,
    float* __restrict__ pm, float* __restrict__ pxc)
{
  __shared__ float s_geo[64][6];              // dfx,dfy,dfz,d2,d0,dist
  __shared__ unsigned short s_m1[64][40];     // bf16 m1, padded (16B-aligned rows)
  __shared__ unsigned short s_c1[64][40];
  __shared__ unsigned short s_we[32][40];     // bf16 e2 weights, rows=f, cols=k
  __shared__ unsigned short s_wc[32][40];

  const int i = blockIdx.x, b = blockIdx.y, chunk = blockIdx.z;
  const int tid = threadIdx.x;
  const int base = b * NATOMS;

  // ---- phase 0 ----
  if (tid < 64){
    const int jj = tid;
    const int j = chunk*64 + jj;
    const float* xi_p = xin + (base + i)*3;
    const float* xj_p = xin + (base + j)*3;
    const float dfx = xi_p[0] - xj_p[0], dfy = xi_p[1] - xj_p[1], dfz = xi_p[2] - xj_p[2];
    const float d2 = dfx*dfx + dfy*dfy + dfz*dfz;
    const float dist = sqrtf(fmaxf(d2, 1e-12f));
    const float* x0i = xyz + (base + i)*4;
    const float* x0j = xyz + (base + j)*4;
    const float q0 = x0i[0]-x0j[0], q1 = x0i[1]-x0j[1], q2 = x0i[2]-x0j[2];
    const float d0 = sqrtf(fmaxf(q0*q0 + q1*q1 + q2*q2, 1e-12f));
    s_geo[jj][0] = dfx; s_geo[jj][1] = dfy; s_geo[jj][2] = dfz;
    s_geo[jj][3] = d2;  s_geo[jj][4] = d0;  s_geo[jj][5] = dist;
  } else {
    const int u = tid - 64;                   // 0..63
    const short8* es = (const short8*)e2wb;   // 128 chunks of 8 bf16
    const short8* cs = (const short8*)c2wb;
#pragma unroll
    for (int h = 0; h < 2; ++h){
      const int c = u + h*64;
      const int f = c >> 2, kq = c & 3;
      *(short8*)&s_we[f][kq*8] = es[c];
      *(short8*)&s_wc[f][kq*8] = cs[c];
    }
  }
  __syncthreads();

  // ---- phase 1: m1/c1 fp32 -> bf16 LDS ----
  {
    const int k = tid & 31, jg = tid >> 5;    // jg 0..3
    const float vpe = vep[(base + i)*32 + k]; // loop-invariant
    const float vpc = vcp[(base + i)*32 + k];
    const float we64 = e1w[k*66 + 64], we65 = e1w[k*66 + 65];
    const float wc64 = c1w[k*66 + 64], wc65 = c1w[k*66 + 65];
#pragma unroll
    for (int jj = jg; jj < 64; jj += 4){
      const float d2 = s_geo[jj][3], d0 = s_geo[jj][4];
      const int j = chunk*64 + jj;
      const float uev = ue[(size_t)(base + j)*32 + k];
      const float m1 = silu_f(fmaf(d2, we64, fmaf(d0, we65, vpe + uev)));
      s_m1[jj][k] = f2bf(m1);
      const float ucv = uc[(size_t)(base + j)*32 + k];
      const float c1 = silu_f(fmaf(d2, wc64, fmaf(d0, wc65, vpc + ucv)));
      s_c1[jj][k] = f2bf(c1);
    }
  }
  __syncthreads();

  // ---- phase 2 ----
  const int lane = tid & 63;
  const int n = lane & 15, quad = lane >> 4;

  if (tid < 64){
    // ======== edge wave ========
    short8 b0 = *(const short8*)&s_we[n][quad*8];
    short8 b1 = *(const short8*)&s_we[16 + n][quad*8];
    f32x4 acc0[4], acc1[4];
#pragma unroll
    for (int jt = 0; jt < 4; ++jt){
      short8 a = *(const short8*)&s_m1[jt*16 + n][quad*8];
      f32x4 z = {0.f, 0.f, 0.f, 0.f};
      acc0[jt] = __builtin_amdgcn_mfma_f32_16x16x32_bf16(a, b0, z, 0, 0, 0);
      acc1[jt] = __builtin_amdgcn_mfma_f32_16x16x32_bf16(a, b1, z, 0, 0, 0);
    }
    const float eb0 = e2b[n], eb1 = e2b[16 + n];
    const float ew0 = eiw[n], ew1 = eiw[16 + n];
    const float ebias = eib[0];
    float ma0 = 0.f, ma1 = 0.f;
#pragma unroll
    for (int jt = 0; jt < 4; ++jt){
      float m20[4], m21[4], g[4];
#pragma unroll
      for (int r = 0; r < 4; ++r){
        m20[r] = silu_f(acc0[jt][r] + eb0);
        m21[r] = silu_f(acc1[jt][r] + eb1);
        g[r] = m20[r]*ew0 + m21[r]*ew1;
      }
#pragma unroll
      for (int r = 0; r < 4; ++r){
        g[r] += __shfl_xor(g[r], 1);
        g[r] += __shfl_xor(g[r], 2);
        g[r] += __shfl_xor(g[r], 4);
        g[r] += __shfl_xor(g[r], 8);
      }
#pragma unroll
      for (int r = 0; r < 4; ++r){
        const int jglob = chunk*64 + jt*16 + quad*4 + r;
        const float e = (jglob == i) ? 0.0f : sigmoid_f(g[r] + ebias);
        ma0 = fmaf(e, m20[r], ma0);
        ma1 = fmaf(e, m21[r], ma1);
      }
    }
    ma0 += __shfl_xor(ma0, 16); ma0 += __shfl_xor(ma0, 32);
    ma1 += __shfl_xor(ma1, 16); ma1 += __shfl_xor(ma1, 32);
    if (lane < 16){
      float* o = pm + ((size_t)(base + i)*3 + chunk)*32;
      o[lane] = ma0;
      o[16 + lane] = ma1;
    }
  } else {
    // ======== coordinate wave ========
    short8 b0 = *(const short8*)&s_wc[n][quad*8];
    short8 b1 = *(const short8*)&s_wc[16 + n][quad*8];
    f32x4 acc0[4], acc1[4];
#pragma unroll
    for (int jt = 0; jt < 4; ++jt){
      short8 a = *(const short8*)&s_c1[jt*16 + n][quad*8];
      f32x4 z = {0.f, 0.f, 0.f, 0.f};
      acc0[jt] = __builtin_amdgcn_mfma_f32_16x16x32_bf16(a, b0, z, 0, 0, 0);
      acc1[jt] = __builtin_amdgcn_mfma_f32_16x16x32_bf16(a, b1, z, 0, 0, 0);
    }
    const float cb0 = c2b[n], cb1 = c2b[16 + n];
    const float cw0 = c3w[n], cw1 = c3w[16 + n];
    const float cbias = c3b[0];
    float px = 0.f, py = 0.f, pz = 0.f;
#pragma unroll
    for (int jt = 0; jt < 4; ++jt){
      float g[4];
#pragma unroll
      for (int r = 0; r < 4; ++r){
        g[r] = silu_f(acc0[jt][r] + cb0)*cw0 + silu_f(acc1[jt][r] + cb1)*cw1;
      }
#pragma unroll
      for (int r = 0; r < 4; ++r){
        g[r] += __shfl_xor(g[r], 1);
        g[r] += __shfl_xor(g[r], 2);
        g[r] += __shfl_xor(g[r], 4);
        g[r] += __shfl_xor(g[r], 8);
      }
#pragma unroll
      for (int r = 0; r < 4; ++r){
        const int jj = jt*16 + quad*4 + r;
        const float s = (g[r] + cbias) * fast_rcp(s_geo[jj][5] + 1.0f);
        px = fmaf(s, s_geo[jj][0], px);
        py = fmaf(s, s_geo[jj][1], py);
        pz = fmaf(s, s_geo[jj][2], pz);
      }
    }
    px += __shfl_xor(px, 16); px += __shfl_xor(px, 32);
    py += __shfl_xor(py, 16); py += __shfl_xor(py, 32);
    pz += __shfl_xor(pz, 16); pz += __shfl_xor(pz, 32);
    if (lane == 0){
      float* o = pxc + ((size_t)(base + i)*3 + chunk)*3;
      o[0] = px; o[1] = py; o[2] = pz;
    }
  }
}

// ---------------- post: finalize layer l + precompute layer l+1 -------------
__global__ __launch_bounds__(256) void k_post(
    float* hln, const float* __restrict__ xin,
    const float* __restrict__ pm, const float* __restrict__ pxc,
    float* __restrict__ hout, float* __restrict__ xout,
    const float* __restrict__ n1w, const float* __restrict__ n1b,
    const float* __restrict__ n2w, const float* __restrict__ n2b,
    const float* __restrict__ lnxg, const float* __restrict__ lnxb,
    const float* __restrict__ lnhg_n, const float* __restrict__ lnhb_n,
    const float* __restrict__ e1w_n, const float* __restrict__ e1b_n,
    const float* __restrict__ c1w_n, const float* __restrict__ c1b_n,
    float* __restrict__ ue, float* __restrict__ uc,
    float* __restrict__ vep, float* __restrict__ vcp)
{
  __shared__ float s_hl[8][33];
  __shared__ float s_mg[8][33];
  __shared__ float s_n1[8][33];
  __shared__ float s_ho[8][33];

  const int tid = threadIdx.x;
  const int il = tid >> 5, f = tid & 31;
  const int node = blockIdx.x*8 + il;

  const float hlf = hln[node*32 + f];
  s_hl[il][f] = hlf;
  const float* pmn = pm + (size_t)node*96;
  s_mg[il][f] = pmn[f] + pmn[32 + f] + pmn[64 + f];
  __syncthreads();

  float a = n1b[f];
  const float* w1 = n1w + f*64;
#pragma unroll
  for (int k = 0; k < 32; ++k) a = fmaf(s_hl[il][k], w1[k], a);
#pragma unroll
  for (int k = 0; k < 32; ++k) a = fmaf(s_mg[il][k], w1[32+k], a);
  s_n1[il][f] = silu_f(a);

  if (f < 3){
    const float* xr = xin + node*3;
    const float x0 = xr[0], x1 = xr[1], x2 = xr[2];
    const float mx = (x0 + x1 + x2) * (1.0f/3.0f);
    const float v0 = x0-mx, v1 = x1-mx, v2 = x2-mx;
    const float r = rsqrtf((v0*v0 + v1*v1 + v2*v2)*(1.0f/3.0f) + 1e-5f);
    const float xv = (f == 0) ? x0 : ((f == 1) ? x1 : x2);
    const float xl = fmaf((xv - mx)*r, lnxg[f], lnxb[f]);
    const float* pc = pxc + (size_t)node*9;
    xout[node*3 + f] = xl + pc[f] + pc[3 + f] + pc[6 + f];
  }
  __syncthreads();

  float o = n2b[f];
  const float* w2 = n2w + f*32;
#pragma unroll
  for (int k = 0; k < 32; ++k) o = fmaf(s_n1[il][k], w2[k], o);
  const float ho = hlf + o;
  hout[node*32 + f] = ho;
  s_ho[il][f] = ho;
  __syncthreads();

  float m = 0.f;
#pragma unroll
  for (int k = 0; k < 32; ++k) m += s_ho[il][k];
  m *= (1.0f/32.0f);
  float v = 0.f;
#pragma unroll
  for (int k = 0; k < 32; ++k){ float d = s_ho[il][k]-m; v = fmaf(d, d, v); }
  const float r = rsqrtf(v*(1.0f/32.0f) + 1e-5f);
  float hl[32];
#pragma unroll
  for (int k = 0; k < 32; ++k) hl[k] = fmaf((s_ho[il][k]-m)*r, lnhg_n[k], lnhb_n[k]);
  hln[node*32 + f] = hl[f];

  const float* we = e1w_n + f*66;
  float sv = e1b_n[f], su = 0.f;
#pragma unroll
  for (int k = 0; k < 32; ++k){ sv = fmaf(hl[k], we[k], sv); su = fmaf(hl[k], we[32+k], su); }
  vep[node*32 + f] = sv;
  ue [node*32 + f] = su;

  const float* wc = c1w_n + f*66;
  float cv = c1b_n[f], cu = 0.f;
#pragma unroll
  for (int k = 0; k < 32; ++k){ cv = fmaf(hl[k], wc[k], cv); cu = fmaf(hl[k], wc[32+k], cu); }
  vcp[node*32 + f] = cv;
  uc [node*32 + f] = cu;
}

// ---------------- epilogue: output heads --------------------------------
__global__ __launch_bounds__(256) void k_final(
    const float* __restrict__ hin, const float* __restrict__ xin,
    const float* __restrict__ xyz,
    const float* __restrict__ how, const float* __restrict__ hob,
    const float* __restrict__ xow, const float* __restrict__ xob,
    float* __restrict__ out)
{
  int g = blockIdx.x * 256 + threadIdx.x;
  if (g >= BATCH*NATOMS) return;
  const float* h = hin + g*32;
  float a = hob[0];
#pragma unroll
  for (int k = 0; k < 32; ++k) a = fmaf(h[k], how[k], a);
  const float* x = xin + g*3;
#pragma unroll
  for (int c = 0; c < 3; ++c){
    float o = xob[c];
    o = fmaf(x[0], xow[c*3+0], o);
    o = fmaf(x[1], xow[c*3+1], o);
    o = fmaf(x[2], xow[c*3+2], o);
    out[g*4 + c] = o - xyz[g*4 + c];
  }
  out[g*4 + 3] = a;
}

extern "C" void kernel_launch(void* const* d_in, const int* in_sizes, int n_in,
                              void* d_out, int out_size, void* d_ws, size_t ws_size,
                              hipStream_t stream)
{
  const float* xyz      = (const float*)d_in[0];
  const float* pdf      = (const float*)d_in[1];
  const float* t        = (const float*)d_in[2];
  const float* emb_in_w = (const float*)d_in[3];
  const float* emb_in_b = (const float*)d_in[4];
  const float* emb_out_w= (const float*)d_in[5];
  const float* emb_out_b= (const float*)d_in[6];
  const float* x_out_w  = (const float*)d_in[7];
  const float* x_out_b  = (const float*)d_in[8];
  const float* pdf_w    = (const float*)d_in[9];
  const float* pdf_b    = (const float*)d_in[10];
  const float* g1w      = (const float*)d_in[11];
  const float* g1b      = (const float*)d_in[12];
  const float* g2w      = (const float*)d_in[13];
  const float* g2b      = (const float*)d_in[14];
  const float* g3w      = (const float*)d_in[15];
  const float* g3b      = (const float*)d_in[16];
  const float* gamma0   = (const float*)d_in[17];
  const float* gamma1   = (const float*)d_in[18];
  const float* lnhg     = (const float*)d_in[19];
  const float* lnhb     = (const float*)d_in[20];
  const float* lnxg     = (const float*)d_in[21];
  const float* lnxb     = (const float*)d_in[22];
  const float* e1w      = (const float*)d_in[23];
  const float* e1b      = (const float*)d_in[24];
  const float* e2w      = (const float*)d_in[25];
  const float* e2b      = (const float*)d_in[26];
  const float* eiw      = (const float*)d_in[27];
  const float* eib      = (const float*)d_in[28];
  const float* n1w      = (const float*)d_in[29];
  const float* n1b      = (const float*)d_in[30];
  const float* n2w      = (const float*)d_in[31];
  const float* n2b      = (const float*)d_in[32];
  const float* c1w      = (const float*)d_in[33];
  const float* c1b      = (const float*)d_in[34];
  const float* c2w      = (const float*)d_in[35];
  const float* c2b      = (const float*)d_in[36];
  const float* c3w      = (const float*)d_in[37];
  const float* c3b      = (const float*)d_in[38];

  const int NTOT = BATCH*NATOMS;          // 1536 nodes
  float* ws   = (float*)d_ws;
  float* temb = ws;                        // 8
  float* pdfe = ws + 8;                    // 80 (pad to 96)
  unsigned short* e2wb = (unsigned short*)(ws + 96);    // 4096 ushort
  unsigned short* c2wb = e2wb + 4096;                   // 4096 ushort
  float* h0   = ws + 96 + 4096;            // (8192 ushort = 4096 floats)
  float* hout = h0   + NTOT*32;
  float* xb0  = hout + NTOT*32;
  float* xb1  = xb0  + NTOT*3;
  float* hln  = xb1  + NTOT*3;
  float* ue   = hln  + NTOT*32;
  float* uc   = ue   + NTOT*32;
  float* vep  = uc   + NTOT*32;
  float* vcp  = vep  + NTOT*32;
  float* pm   = vcp  + NTOT*32;            // 1536*96
  float* pxc  = pm   + NTOT*96;            // 1536*9

  k_prelude<<<88, 256, 0, stream>>>(pdf, t, pdf_w, pdf_b,
      g1w, g1b, g2w, g2b, g3w, g3b, gamma0, gamma1, temb, pdfe);
  k_embed<<<(NTOT*HF + 255)/256, 256, 0, stream>>>(
      xyz, temb, pdfe, emb_in_w, emb_in_b, h0, xb0);
  k_wprep<<<16, 256, 0, stream>>>(e2w, c2w, e2wb, c2wb);
  k_node<<<(NTOT*32 + 255)/256, 256, 0, stream>>>(
      h0, lnhg, lnhb, e1w, e1b, c1w, c1b, hln, ue, uc, vep, vcp);

  const float* xcur = xb0; float* xnext = xb1;
  for (int l = 0; l < 4; ++l){
    const int n = (l < 3) ? (l + 1) : 3;   // next-layer weights for precompute
    k_pair<<<dim3(NATOMS, BATCH, 3), 128, 0, stream>>>(
        xcur, xyz, ue, uc, vep, vcp,
        e1w + l*2112, c1w + l*2112,
        e2wb + l*1024, c2wb + l*1024,
        e2b + l*32, eiw + l*32, eib + l,
        c2b + l*32, c3w + l*32, c3b + l,
        pm, pxc);
    k_post<<<NTOT/8, 256, 0, stream>>>(
        hln, xcur, pm, pxc, hout, xnext,
        n1w + l*2048, n1b + l*32, n2w + l*1024, n2b + l*32,
        lnxg + l*3, lnxb + l*3,
        lnhg + n*32, lnhb + n*32, e1w + n*2112, e1b + n*32,
        c1w + n*2112, c1b + n*32,
        ue, uc, vep, vcp);
    const float* tx = xcur; xcur = xnext; xnext = (float*)tx;
  }

  k_final<<<(NTOT + 255)/256, 256, 0, stream>>>(
      hout, xcur, xyz, emb_out_w, emb_out_b, x_out_w, x_out_b, (float*)d_out);
}